// Round 2
// baseline (619.627 us; speedup 1.0000x reference)
//
#include <hip/hip_runtime.h>
#include <hip/hip_bf16.h>
#include <math.h>

#define N_NODES 100000
#define N_EDGES 1600000
#define DIM_IN 165
#define DIM_HID 128
#define SCAN_CHUNK 1024
#define NSCAN_BLK ((N_NODES + SCAN_CHUNK - 1) / SCAN_CHUNK)  // 98

// ---------- edge_index dtype detection (int32 vs int64 on device) ----------
// If stored int64 (little-endian, values < 2^31), every odd 32-bit word is 0.
// P(16 random int32 indices in [0,100000) all == 0) ~ 1e-80 -> robust.
__global__ void k_detect(const int* __restrict__ e32, int* __restrict__ flag) {
    if (threadIdx.x == 0 && blockIdx.x == 0) {
        int z = 0;
        for (int k = 0; k < 16; ++k) z |= e32[2 * k + 1];
        flag[0] = (z == 0) ? 1 : 0;
    }
}

__global__ void k_convert(const int* __restrict__ e32, const int* __restrict__ flag,
                          int* __restrict__ outIdx) {
    long long i = (long long)blockIdx.x * 256 + threadIdx.x;
    if (i < 2LL * N_EDGES) {
        if (flag[0]) outIdx[i] = (int)((const long long*)e32)[i];
        else         outIdx[i] = e32[i];
    }
}

// ---------- weight transpose: [128][165] -> [165][128] for coalesced reads ----------
__global__ void k_transpose(const float* __restrict__ Wrel, const float* __restrict__ Wroot,
                            float* __restrict__ Wt_rel, float* __restrict__ Wt_root) {
    int j = blockIdx.x * blockDim.x + threadIdx.x;
    if (j < DIM_IN * DIM_HID) {
        int d = j >> 7, o = j & 127;
        Wt_rel[j]  = Wrel[o * DIM_IN + d];
        Wt_root[j] = Wroot[o * DIM_IN + d];
    }
}

__global__ void k_zero(int* __restrict__ p, int n) {
    int i = blockIdx.x * blockDim.x + threadIdx.x;
    if (i < n) p[i] = 0;
}

// ---------- CSR build ----------
__global__ void k_hist(const int* __restrict__ dst, int* __restrict__ cnt) {
    int e = blockIdx.x * blockDim.x + threadIdx.x;
    if (e < N_EDGES) atomicAdd(&cnt[dst[e]], 1);
}

__global__ void k_scan1(const int* __restrict__ cnt, int* __restrict__ blkSum) {
    __shared__ int lds[256];
    int t = threadIdx.x;
    int base = blockIdx.x * SCAN_CHUNK + t * 4;
    int s = 0;
    #pragma unroll
    for (int k = 0; k < 4; ++k) { int i = base + k; if (i < N_NODES) s += cnt[i]; }
    lds[t] = s; __syncthreads();
    for (int o = 128; o > 0; o >>= 1) {
        if (t < o) lds[t] += lds[t + o];
        __syncthreads();
    }
    if (t == 0) blkSum[blockIdx.x] = lds[0];
}

__global__ void k_scan2(const int* __restrict__ blkSum, int* __restrict__ blkOff,
                        int* __restrict__ row_ptr) {
    if (threadIdx.x == 0 && blockIdx.x == 0) {
        int run = 0;
        for (int b = 0; b < NSCAN_BLK; ++b) { blkOff[b] = run; run += blkSum[b]; }
        row_ptr[N_NODES] = run;  // == N_EDGES
    }
}

__global__ void k_scan3(const int* __restrict__ cnt, const int* __restrict__ blkOff,
                        int* __restrict__ row_ptr, int* __restrict__ cursor) {
    __shared__ int lds[256];
    int t = threadIdx.x;
    int base = blockIdx.x * SCAN_CHUNK + t * 4;
    int c[4]; int ts = 0;
    #pragma unroll
    for (int k = 0; k < 4; ++k) { int i = base + k; c[k] = (i < N_NODES) ? cnt[i] : 0; ts += c[k]; }
    lds[t] = ts; __syncthreads();
    for (int o = 1; o < 256; o <<= 1) {
        int v = lds[t]; int add = (t >= o) ? lds[t - o] : 0;
        __syncthreads(); lds[t] = v + add; __syncthreads();
    }
    int excl = lds[t] - ts;
    int p = blkOff[blockIdx.x] + excl;
    #pragma unroll
    for (int k = 0; k < 4; ++k) {
        int i = base + k;
        if (i < N_NODES) { row_ptr[i] = p; cursor[i] = p; }
        p += c[k];
    }
}

__global__ void k_place(const int* __restrict__ src, const int* __restrict__ dst,
                        int* __restrict__ cursor, int* __restrict__ esrc) {
    int e = blockIdx.x * blockDim.x + threadIdx.x;
    if (e < N_EDGES) {
        int d = dst[e];
        int pos = atomicAdd(&cursor[d], 1);
        esrc[pos] = src[e];
    }
}

// ---------- layer-1 GEMMs: y_rel = x@W_rel1^T, y_root = x@W_root1^T ----------
// block = 256 threads (4 waves), 32 nodes/block, wave handles 8 nodes,
// lane l owns output columns (2l, 2l+1) as float2.
__launch_bounds__(256, 2)
__global__ void k_gemm1(const float* __restrict__ x, const float* __restrict__ Wt_rel,
                        const float* __restrict__ Wt_root,
                        float* __restrict__ y_rel, float* __restrict__ y_root) {
    __shared__ float xs[32 * DIM_IN];  // 21.1 KB, 32 contiguous rows of x
    int tid = threadIdx.x;
    int base = blockIdx.x * 32;
    const float4* xg = (const float4*)(x + (size_t)base * DIM_IN);
    float4* xl = (float4*)xs;
    #pragma unroll 2
    for (int i = tid; i < (32 * DIM_IN) / 4; i += 256) xl[i] = xg[i];
    __syncthreads();

    int w = tid >> 6, lane = tid & 63;
    const float2* wr = (const float2*)Wt_rel;
    const float2* wo = (const float2*)Wt_root;
    float2 ar[8], ao[8];
    #pragma unroll
    for (int k = 0; k < 8; ++k) { ar[k] = make_float2(0.f, 0.f); ao[k] = make_float2(0.f, 0.f); }
    const float* xrow = xs + (w * 8) * DIM_IN;

    for (int d = 0; d < DIM_IN; ++d) {
        float2 a = wr[d * 64 + lane];   // L1/L2-resident weight stream
        float2 b = wo[d * 64 + lane];
        #pragma unroll
        for (int k = 0; k < 8; ++k) {
            float xv = xrow[k * DIM_IN + d];  // LDS broadcast
            ar[k].x = fmaf(xv, a.x, ar[k].x); ar[k].y = fmaf(xv, a.y, ar[k].y);
            ao[k].x = fmaf(xv, b.x, ao[k].x); ao[k].y = fmaf(xv, b.y, ao[k].y);
        }
    }
    float2* yr = (float2*)y_rel;
    float2* yo = (float2*)y_root;
    #pragma unroll
    for (int k = 0; k < 8; ++k) {
        int n = base + w * 8 + k;
        yr[(size_t)n * 64 + lane] = ar[k];
        yo[(size_t)n * 64 + lane] = ao[k];
    }
}

// ---------- fused: agg = sum_{j->i} y_rel[j]; h = relu(agg+b+y_root);
//            s = h.W_rel2; r = h.W_root2 (one wave per node) ----------
__launch_bounds__(256, 2)
__global__ void k_agg(const float* __restrict__ y_rel, const float* __restrict__ y_root,
                      const int* __restrict__ row_ptr, const int* __restrict__ esrc,
                      const float* __restrict__ b_rel1, const float* __restrict__ W_rel2,
                      const float* __restrict__ W_root2,
                      float* __restrict__ s_out, float* __restrict__ r_out) {
    int node = blockIdx.x * 4 + (threadIdx.x >> 6);
    int lane = threadIdx.x & 63;
    const float2* yr = (const float2*)y_rel;
    int e0 = row_ptr[node], e1 = row_ptr[node + 1];
    float2 acc0 = make_float2(0.f, 0.f), acc1 = make_float2(0.f, 0.f);
    int e = e0;
    for (; e + 1 < e1; e += 2) {        // 2-deep to break load latency chain
        int s0 = esrc[e], s1 = esrc[e + 1];
        float2 v0 = yr[(size_t)s0 * 64 + lane];
        float2 v1 = yr[(size_t)s1 * 64 + lane];
        acc0.x += v0.x; acc0.y += v0.y;
        acc1.x += v1.x; acc1.y += v1.y;
    }
    if (e < e1) {
        int s0 = esrc[e];
        float2 v0 = yr[(size_t)s0 * 64 + lane];
        acc0.x += v0.x; acc0.y += v0.y;
    }
    float ax = acc0.x + acc1.x, ay = acc0.y + acc1.y;

    float2 b2  = ((const float2*)b_rel1)[lane];
    float2 rt  = ((const float2*)y_root)[(size_t)node * 64 + lane];
    float hx = ax + b2.x + rt.x; hx = hx > 0.f ? hx : 0.f;
    float hy = ay + b2.y + rt.y; hy = hy > 0.f ? hy : 0.f;
    float2 wr2 = ((const float2*)W_rel2)[lane];
    float2 wo2 = ((const float2*)W_root2)[lane];
    float sd = fmaf(hx, wr2.x, hy * wr2.y);
    float rd = fmaf(hx, wo2.x, hy * wo2.y);
    #pragma unroll
    for (int o = 32; o > 0; o >>= 1) {
        sd += __shfl_down(sd, o);
        rd += __shfl_down(rd, o);
    }
    if (lane == 0) { s_out[node] = sd; r_out[node] = rd; }
}

// ---------- final: out[i] = sigmoid(sum_{j->i} s[j] + b2 + r[i]) ----------
__global__ void k_final(const float* __restrict__ s_in, const float* __restrict__ r_in,
                        const int* __restrict__ row_ptr, const int* __restrict__ esrc,
                        const float* __restrict__ b_rel2, float* __restrict__ out) {
    int i = blockIdx.x * blockDim.x + threadIdx.x;
    if (i < N_NODES) {
        int e0 = row_ptr[i], e1 = row_ptr[i + 1];
        float sum = 0.f;
        for (int e = e0; e < e1; ++e) sum += s_in[esrc[e]];  // s is 400KB, L2-hot
        float z = sum + b_rel2[0] + r_in[i];
        out[i] = 1.f / (1.f + expf(-z));
    }
}

extern "C" void kernel_launch(void* const* d_in, const int* in_sizes, int n_in,
                              void* d_out, int out_size, void* d_ws, size_t ws_size,
                              hipStream_t stream) {
    const float* x      = (const float*)d_in[0];
    const int*   eidx   = (const int*)d_in[1];
    const float* Wrel1  = (const float*)d_in[2];
    const float* brel1  = (const float*)d_in[3];
    const float* Wroot1 = (const float*)d_in[4];
    const float* Wrel2  = (const float*)d_in[5];
    const float* brel2  = (const float*)d_in[6];
    const float* Wroot2 = (const float*)d_in[7];
    float* out = (float*)d_out;

    // Bump allocator over d_ws with lifetime overlap to cut peak usage.
    // Persistent region first, then a union region: CSR-build scratch
    // (conv/cnt/cursor/blkSum/blkOff, dead after k_place) overlapped with
    // y_rel/y_root (born at k_gemm1, which runs after k_place).
    char* basep = (char*)d_ws;
    size_t off = 0;
    auto alloc = [&](size_t bytes) -> void* {
        off = (off + 511) & ~(size_t)511;
        void* r = basep + off;
        off += bytes;
        return r;
    };
    // --- persistent ---
    int*   flag    = (int*)alloc(4);
    float* Wt_rel  = (float*)alloc((size_t)DIM_IN * DIM_HID * 4);
    float* Wt_root = (float*)alloc((size_t)DIM_IN * DIM_HID * 4);
    int*   row_ptr = (int*)alloc((size_t)(N_NODES + 1) * 4);
    int*   esrc    = (int*)alloc((size_t)N_EDGES * 4);
    float* s_buf   = (float*)alloc((size_t)N_NODES * 4);
    float* r_buf   = (float*)alloc((size_t)N_NODES * 4);
    // --- union region ---
    size_t union_base = (off + 511) & ~(size_t)511;
    // lifetime A: CSR scratch (dead after k_place)
    off = union_base;
    int*   conv    = (int*)alloc((size_t)2 * N_EDGES * 4);
    int*   cnt     = (int*)alloc((size_t)N_NODES * 4);
    int*   cursor  = (int*)alloc((size_t)N_NODES * 4);
    int*   blkSum  = (int*)alloc((size_t)NSCAN_BLK * 4);
    int*   blkOff  = (int*)alloc((size_t)NSCAN_BLK * 4);
    size_t endA = off;
    // lifetime B: layer-1 GEMM outputs (born after k_place)
    off = union_base;
    float* y_rel   = (float*)alloc((size_t)N_NODES * DIM_HID * 4);
    float* y_root  = (float*)alloc((size_t)N_NODES * DIM_HID * 4);
    size_t endB = off;
    (void)endA; (void)endB;   // peak = max(endA, endB) ≈ 111 MB

    const int* srcp = conv;
    const int* dstp = conv + N_EDGES;

    hipLaunchKernelGGL(k_detect,    dim3(1),     dim3(64),  0, stream, eidx, flag);
    hipLaunchKernelGGL(k_convert,   dim3(12500), dim3(256), 0, stream, eidx, flag, conv);
    hipLaunchKernelGGL(k_transpose, dim3(83),    dim3(256), 0, stream, Wrel1, Wroot1, Wt_rel, Wt_root);
    hipLaunchKernelGGL(k_zero,      dim3(391),   dim3(256), 0, stream, cnt, N_NODES);
    hipLaunchKernelGGL(k_hist,      dim3(6250),  dim3(256), 0, stream, dstp, cnt);
    hipLaunchKernelGGL(k_scan1,     dim3(NSCAN_BLK), dim3(256), 0, stream, cnt, blkSum);
    hipLaunchKernelGGL(k_scan2,     dim3(1),     dim3(64),  0, stream, blkSum, blkOff, row_ptr);
    hipLaunchKernelGGL(k_scan3,     dim3(NSCAN_BLK), dim3(256), 0, stream, cnt, blkOff, row_ptr, cursor);
    hipLaunchKernelGGL(k_place,     dim3(6250),  dim3(256), 0, stream, srcp, dstp, cursor, esrc);
    hipLaunchKernelGGL(k_gemm1,     dim3(3125),  dim3(256), 0, stream, x, Wt_rel, Wt_root, y_rel, y_root);
    hipLaunchKernelGGL(k_agg,       dim3(25000), dim3(256), 0, stream, y_rel, y_root, row_ptr, esrc,
                       brel1, Wrel2, Wroot2, s_buf, r_buf);
    hipLaunchKernelGGL(k_final,     dim3(391),   dim3(256), 0, stream, s_buf, r_buf, row_ptr, esrc,
                       brel2, out);
}

// Round 3
// 452.065 us; speedup vs baseline: 1.3707x; 1.3707x over previous
//
#include <hip/hip_runtime.h>
#include <hip/hip_bf16.h>
#include <math.h>

#define N_NODES 100000
#define N_EDGES 1600000
#define DIM_IN 165
#define DIM_HID 128
#define K_PAD 192                 // 6 chunks of 32
#define SCAN_CHUNK 1024
#define NSCAN_BLK ((N_NODES + SCAN_CHUNK - 1) / SCAN_CHUNK)  // 98

typedef __attribute__((ext_vector_type(8))) short short8v;   // 8 bf16 (4 VGPR)
typedef __attribute__((ext_vector_type(4))) float f32x4;     // MFMA acc

// ---------- edge_index dtype detection (int32 vs int64 on device) ----------
__global__ void k_detect(const int* __restrict__ e32, int* __restrict__ flag) {
    if (threadIdx.x == 0 && blockIdx.x == 0) {
        int z = 0;
        for (int k = 0; k < 16; ++k) z |= e32[2 * k + 1];
        flag[0] = (z == 0) ? 1 : 0;
    }
}

__global__ void k_convert(const int* __restrict__ e32, const int* __restrict__ flag,
                          int* __restrict__ outIdx) {
    long long i = (long long)blockIdx.x * 256 + threadIdx.x;
    if (i < 2LL * N_EDGES) {
        if (flag[0]) outIdx[i] = (int)((const long long*)e32)[i];
        else         outIdx[i] = e32[i];
    }
}

// ---------- W prep: pack [Wrel1 ; Wroot1] as bf16 frag-layout Wpk[k>>3][n][k&7] ----------
// flat idx = ((k>>3)*256 + n)*8 + (k&7); zero-pad k in [165,192).
__global__ void k_prepw(const float* __restrict__ Wrel1, const float* __restrict__ Wroot1,
                        unsigned short* __restrict__ Wpk) {
    int idx = blockIdx.x * 256 + threadIdx.x;
    if (idx < (K_PAD / 8) * 256 * 8) {
        int j = idx & 7;
        int n = (idx >> 3) & 255;
        int p = idx >> 11;
        int k = p * 8 + j;
        float v = 0.f;
        if (k < DIM_IN) v = (n < 128) ? Wrel1[n * DIM_IN + k] : Wroot1[(n - 128) * DIM_IN + k];
        unsigned u = __float_as_uint(v);
        u += 0x7FFFu + ((u >> 16) & 1u);     // RNE to bf16
        Wpk[idx] = (unsigned short)(u >> 16);
    }
}

__global__ void k_zero(int* __restrict__ p, int n) {
    int i = blockIdx.x * blockDim.x + threadIdx.x;
    if (i < n) p[i] = 0;
}

// ---------- CSR build ----------
__global__ void k_hist(const int* __restrict__ dst, int* __restrict__ cnt) {
    int e = blockIdx.x * blockDim.x + threadIdx.x;
    if (e < N_EDGES) atomicAdd(&cnt[dst[e]], 1);
}

__global__ void k_scan1(const int* __restrict__ cnt, int* __restrict__ blkSum) {
    __shared__ int lds[256];
    int t = threadIdx.x;
    int base = blockIdx.x * SCAN_CHUNK + t * 4;
    int s = 0;
    #pragma unroll
    for (int k = 0; k < 4; ++k) { int i = base + k; if (i < N_NODES) s += cnt[i]; }
    lds[t] = s; __syncthreads();
    for (int o = 128; o > 0; o >>= 1) {
        if (t < o) lds[t] += lds[t + o];
        __syncthreads();
    }
    if (t == 0) blkSum[blockIdx.x] = lds[0];
}

__global__ void k_scan2(const int* __restrict__ blkSum, int* __restrict__ blkOff,
                        int* __restrict__ row_ptr) {
    if (threadIdx.x == 0 && blockIdx.x == 0) {
        int run = 0;
        for (int b = 0; b < NSCAN_BLK; ++b) { blkOff[b] = run; run += blkSum[b]; }
        row_ptr[N_NODES] = run;
    }
}

__global__ void k_scan3(const int* __restrict__ cnt, const int* __restrict__ blkOff,
                        int* __restrict__ row_ptr, int* __restrict__ cursor) {
    __shared__ int lds[256];
    int t = threadIdx.x;
    int base = blockIdx.x * SCAN_CHUNK + t * 4;
    int c[4]; int ts = 0;
    #pragma unroll
    for (int k = 0; k < 4; ++k) { int i = base + k; c[k] = (i < N_NODES) ? cnt[i] : 0; ts += c[k]; }
    lds[t] = ts; __syncthreads();
    for (int o = 1; o < 256; o <<= 1) {
        int v = lds[t]; int add = (t >= o) ? lds[t - o] : 0;
        __syncthreads(); lds[t] = v + add; __syncthreads();
    }
    int excl = lds[t] - ts;
    int p = blkOff[blockIdx.x] + excl;
    #pragma unroll
    for (int k = 0; k < 4; ++k) {
        int i = base + k;
        if (i < N_NODES) { row_ptr[i] = p; cursor[i] = p; }
        p += c[k];
    }
}

__global__ void k_place(const int* __restrict__ src, const int* __restrict__ dst,
                        int* __restrict__ cursor, int* __restrict__ esrc) {
    int e = blockIdx.x * blockDim.x + threadIdx.x;
    if (e < N_EDGES) {
        int d = dst[e];
        int pos = atomicAdd(&cursor[d], 1);
        esrc[pos] = src[e];
    }
}

// ---------- layer-1 via MFMA: [y_rel | y_root] = x @ [Wrel1;Wroot1]^T ----------
// M-tile 32 rows/block, 4 waves: wave w -> rows (w&1)*16.., cols (w>>1)*128..
// x split hi+lo bf16 (2 MFMA passes, same acc) to keep precision ~fp32-grade.
// y_rel stored bf16 (halves k_agg gather bytes), y_root fp32.
__launch_bounds__(256, 4)
__global__ void k_gemm_mfma(const float* __restrict__ x, const unsigned short* __restrict__ Wpk,
                            unsigned short* __restrict__ y_rel, float* __restrict__ y_root) {
    // stride 232 ushorts = 464 B: 16B-aligned rows, bank stride 20 mod 32 -> 2-way (free)
    __shared__ unsigned short lh[32][232];
    __shared__ unsigned short ll[32][232];
    int tid = threadIdx.x;
    int base = blockIdx.x * 32;

    // stage 32 rows of x (5280 floats = 1320 float4, 16B-aligned since 32*165*4 = 21120)
    const float4* xg = (const float4*)(x + (size_t)base * DIM_IN);
    for (int i = tid; i < 1320; i += 256) {
        float4 v = xg[i];
        int fi = i * 4;
        #pragma unroll
        for (int e = 0; e < 4; ++e) {
            int idx = fi + e;
            int r = idx / DIM_IN;            // magic-mul (compile-time const)
            int k = idx - r * DIM_IN;
            float f = (e == 0) ? v.x : (e == 1) ? v.y : (e == 2) ? v.z : v.w;
            unsigned u = __float_as_uint(f);
            unsigned short hi = (unsigned short)(u >> 16);          // truncate
            float fhi = __uint_as_float(u & 0xFFFF0000u);
            float lo = f - fhi;                                      // exact residual
            unsigned short lob = (unsigned short)(__float_as_uint(lo) >> 16);
            lh[r][k] = hi;
            ll[r][k] = lob;
        }
    }
    // zero-pad k in [165,192)
    for (int i = tid; i < 32 * (K_PAD - DIM_IN); i += 256) {
        int r = i / (K_PAD - DIM_IN);
        int k = DIM_IN + (i - r * (K_PAD - DIM_IN));
        lh[r][k] = 0; ll[r][k] = 0;
    }
    __syncthreads();

    int w = tid >> 6, l = tid & 63;
    int rowg = w & 1;                 // which 16-row half
    int colh = w >> 1;                // which 128-col half (0:rel, 1:root)
    int m = l & 15, kg = l >> 4;
    int arow = rowg * 16 + m;

    f32x4 acc[8];
    #pragma unroll
    for (int t = 0; t < 8; ++t) acc[t] = (f32x4){0.f, 0.f, 0.f, 0.f};

    const short8v* ap_h = (const short8v*)(&lh[arow][0]);
    const short8v* ap_l = (const short8v*)(&ll[arow][0]);
    const short8v* bp   = (const short8v*)Wpk;
    int bidx = kg * 256 + colh * 128 + m;   // + kc*1024 + t*16

    #pragma unroll
    for (int kc = 0; kc < 6; ++kc) {
        short8v ah = ap_h[kc * 4 + kg];
        short8v al = ap_l[kc * 4 + kg];
        short8v b[8];
        #pragma unroll
        for (int t = 0; t < 8; ++t) b[t] = bp[bidx + kc * 1024 + t * 16];
        #pragma unroll
        for (int t = 0; t < 8; ++t)
            acc[t] = __builtin_amdgcn_mfma_f32_16x16x32_bf16(ah, b[t], acc[t], 0, 0, 0);
        #pragma unroll
        for (int t = 0; t < 8; ++t)
            acc[t] = __builtin_amdgcn_mfma_f32_16x16x32_bf16(al, b[t], acc[t], 0, 0, 0);
    }

    // epilogue: C/D layout col = l&15, row = (l>>4)*4 + q  [m89-verified]
    int orow = base + rowg * 16 + kg * 4;
    if (colh == 0) {
        #pragma unroll
        for (int t = 0; t < 8; ++t) {
            #pragma unroll
            for (int q = 0; q < 4; ++q) {
                unsigned u = __float_as_uint(acc[t][q]);
                u += 0x7FFFu + ((u >> 16) & 1u);                    // RNE to bf16
                y_rel[(size_t)(orow + q) * 128 + t * 16 + m] = (unsigned short)(u >> 16);
            }
        }
    } else {
        #pragma unroll
        for (int t = 0; t < 8; ++t) {
            #pragma unroll
            for (int q = 0; q < 4; ++q)
                y_root[(size_t)(orow + q) * 128 + t * 16 + m] = acc[t][q];
        }
    }
}

// ---------- fused: agg = sum y_rel[j] (bf16 gather, fp32 accum); h = relu(agg+b+y_root);
//            s = h.W_rel2; r = h.W_root2 (one wave per node) ----------
__launch_bounds__(256, 2)
__global__ void k_agg(const unsigned short* __restrict__ y_rel, const float* __restrict__ y_root,
                      const int* __restrict__ row_ptr, const int* __restrict__ esrc,
                      const float* __restrict__ b_rel1, const float* __restrict__ W_rel2,
                      const float* __restrict__ W_root2,
                      float* __restrict__ s_out, float* __restrict__ r_out) {
    int node = blockIdx.x * 4 + (threadIdx.x >> 6);
    int lane = threadIdx.x & 63;
    const unsigned* yr = (const unsigned*)y_rel;   // 2 bf16 per uint; lane owns cols 2l,2l+1
    int e0 = row_ptr[node], e1 = row_ptr[node + 1];
    float ax0 = 0.f, ay0 = 0.f, ax1 = 0.f, ay1 = 0.f;
    float ax2 = 0.f, ay2 = 0.f, ax3 = 0.f, ay3 = 0.f;
    int e = e0;
    for (; e + 3 < e1; e += 4) {                  // 4-deep MLP
        int s0 = esrc[e], s1 = esrc[e + 1], s2 = esrc[e + 2], s3 = esrc[e + 3];
        unsigned v0 = yr[(size_t)s0 * 64 + lane];
        unsigned v1 = yr[(size_t)s1 * 64 + lane];
        unsigned v2 = yr[(size_t)s2 * 64 + lane];
        unsigned v3 = yr[(size_t)s3 * 64 + lane];
        ax0 += __uint_as_float(v0 << 16); ay0 += __uint_as_float(v0 & 0xFFFF0000u);
        ax1 += __uint_as_float(v1 << 16); ay1 += __uint_as_float(v1 & 0xFFFF0000u);
        ax2 += __uint_as_float(v2 << 16); ay2 += __uint_as_float(v2 & 0xFFFF0000u);
        ax3 += __uint_as_float(v3 << 16); ay3 += __uint_as_float(v3 & 0xFFFF0000u);
    }
    for (; e < e1; ++e) {
        unsigned v0 = yr[(size_t)esrc[e] * 64 + lane];
        ax0 += __uint_as_float(v0 << 16); ay0 += __uint_as_float(v0 & 0xFFFF0000u);
    }
    float ax = (ax0 + ax1) + (ax2 + ax3);
    float ay = (ay0 + ay1) + (ay2 + ay3);

    float2 b2 = ((const float2*)b_rel1)[lane];
    float2 rt = ((const float2*)y_root)[(size_t)node * 64 + lane];
    float hx = ax + b2.x + rt.x; hx = hx > 0.f ? hx : 0.f;
    float hy = ay + b2.y + rt.y; hy = hy > 0.f ? hy : 0.f;
    float2 wr2 = ((const float2*)W_rel2)[lane];
    float2 wo2 = ((const float2*)W_root2)[lane];
    float sd = fmaf(hx, wr2.x, hy * wr2.y);
    float rd = fmaf(hx, wo2.x, hy * wo2.y);
    #pragma unroll
    for (int o = 32; o > 0; o >>= 1) {
        sd += __shfl_down(sd, o);
        rd += __shfl_down(rd, o);
    }
    if (lane == 0) { s_out[node] = sd; r_out[node] = rd; }
}

// ---------- final: out[i] = sigmoid(sum_{j->i} s[j] + b2 + r[i]) ----------
__global__ void k_final(const float* __restrict__ s_in, const float* __restrict__ r_in,
                        const int* __restrict__ row_ptr, const int* __restrict__ esrc,
                        const float* __restrict__ b_rel2, float* __restrict__ out) {
    int i = blockIdx.x * blockDim.x + threadIdx.x;
    if (i < N_NODES) {
        int e0 = row_ptr[i], e1 = row_ptr[i + 1];
        float sum = 0.f;
        for (int e = e0; e < e1; ++e) sum += s_in[esrc[e]];  // 400KB, L2-hot
        float z = sum + b_rel2[0] + r_in[i];
        out[i] = 1.f / (1.f + expf(-z));
    }
}

extern "C" void kernel_launch(void* const* d_in, const int* in_sizes, int n_in,
                              void* d_out, int out_size, void* d_ws, size_t ws_size,
                              hipStream_t stream) {
    const float* x      = (const float*)d_in[0];
    const int*   eidx   = (const int*)d_in[1];
    const float* Wrel1  = (const float*)d_in[2];
    const float* brel1  = (const float*)d_in[3];
    const float* Wroot1 = (const float*)d_in[4];
    const float* Wrel2  = (const float*)d_in[5];
    const float* brel2  = (const float*)d_in[6];
    const float* Wroot2 = (const float*)d_in[7];
    float* out = (float*)d_out;

    char* basep = (char*)d_ws;
    size_t off = 0;
    auto alloc = [&](size_t bytes) -> void* {
        off = (off + 511) & ~(size_t)511;
        void* r = basep + off;
        off += bytes;
        return r;
    };
    // --- persistent ---
    int*   flag    = (int*)alloc(4);
    unsigned short* Wpk = (unsigned short*)alloc((size_t)(K_PAD / 8) * 256 * 8 * 2);
    int*   row_ptr = (int*)alloc((size_t)(N_NODES + 1) * 4);
    int*   esrc    = (int*)alloc((size_t)N_EDGES * 4);
    float* s_buf   = (float*)alloc((size_t)N_NODES * 4);
    float* r_buf   = (float*)alloc((size_t)N_NODES * 4);
    // --- union region: CSR scratch (dead after k_place) vs GEMM outputs ---
    size_t union_base = (off + 511) & ~(size_t)511;
    off = union_base;
    int*   conv    = (int*)alloc((size_t)2 * N_EDGES * 4);
    int*   cnt     = (int*)alloc((size_t)N_NODES * 4);
    int*   cursor  = (int*)alloc((size_t)N_NODES * 4);
    int*   blkSum  = (int*)alloc((size_t)NSCAN_BLK * 4);
    int*   blkOff  = (int*)alloc((size_t)NSCAN_BLK * 4);
    off = union_base;
    unsigned short* y_rel = (unsigned short*)alloc((size_t)N_NODES * DIM_HID * 2);
    float*          y_root = (float*)alloc((size_t)N_NODES * DIM_HID * 4);

    const int* srcp = conv;
    const int* dstp = conv + N_EDGES;

    hipLaunchKernelGGL(k_detect,    dim3(1),     dim3(64),  0, stream, eidx, flag);
    hipLaunchKernelGGL(k_convert,   dim3(12500), dim3(256), 0, stream, eidx, flag, conv);
    hipLaunchKernelGGL(k_prepw,     dim3(192),   dim3(256), 0, stream, Wrel1, Wroot1, Wpk);
    hipLaunchKernelGGL(k_zero,      dim3(391),   dim3(256), 0, stream, cnt, N_NODES);
    hipLaunchKernelGGL(k_hist,      dim3(6250),  dim3(256), 0, stream, dstp, cnt);
    hipLaunchKernelGGL(k_scan1,     dim3(NSCAN_BLK), dim3(256), 0, stream, cnt, blkSum);
    hipLaunchKernelGGL(k_scan2,     dim3(1),     dim3(64),  0, stream, blkSum, blkOff, row_ptr);
    hipLaunchKernelGGL(k_scan3,     dim3(NSCAN_BLK), dim3(256), 0, stream, cnt, blkOff, row_ptr, cursor);
    hipLaunchKernelGGL(k_place,     dim3(6250),  dim3(256), 0, stream, srcp, dstp, cursor, esrc);
    hipLaunchKernelGGL(k_gemm_mfma, dim3(3125),  dim3(256), 0, stream, x, Wpk, y_rel, y_root);
    hipLaunchKernelGGL(k_agg,       dim3(25000), dim3(256), 0, stream, y_rel, y_root, row_ptr, esrc,
                       brel1, Wrel2, Wroot2, s_buf, r_buf);
    hipLaunchKernelGGL(k_final,     dim3(391),   dim3(256), 0, stream, s_buf, r_buf, row_ptr, esrc,
                       brel2, out);
}

// Round 8
// 314.851 us; speedup vs baseline: 1.9680x; 1.4358x over previous
//
#include <hip/hip_runtime.h>
#include <hip/hip_bf16.h>
#include <math.h>

#define N_NODES 100000
#define N_EDGES 1600000
#define DIM_IN 165
#define DIM_HID 128
#define K_PAD 192                 // 6 chunks of 32
#define NBUCK 391                 // ceil(100000/256) coarse buckets (dst>>8)
#define EPB 16384                 // edges per block in phases A/B
#define NHB 98                    // ceil(N_EDGES/EPB)
#define CAP 6144                  // per-bucket edge capacity (mean 4092, sigma~64)

typedef __attribute__((ext_vector_type(8))) short short8v;   // 8 bf16 (4 VGPR)
typedef __attribute__((ext_vector_type(4))) float f32x4;     // MFMA acc

// ---------- detect edge dtype (int32 vs int64) + zero bucket counts ----------
__global__ void k_detect(const int* __restrict__ e32, int* __restrict__ flag,
                         int* __restrict__ gcount) {
    int t = threadIdx.x;
    if (t == 0) {
        int z = 0;
        for (int k = 0; k < 16; ++k) z |= e32[2 * k + 1];
        flag[0] = (z == 0) ? 1 : 0;   // 1 => int64 little-endian
    }
    if (t < NBUCK) gcount[t] = 0;
}

// ---------- phase A: per-block bucket histogram + claim global bases ----------
__global__ void k_histB(const int* __restrict__ e32, const int* __restrict__ flag,
                        int* __restrict__ gcount, int* __restrict__ blockBase) {
    __shared__ int lc[NBUCK];
    int t = threadIdx.x;
    for (int i = t; i < NBUCK; i += 256) lc[i] = 0;
    __syncthreads();
    int isI64 = flag[0];
    int base = blockIdx.x * EPB;
    int lim = base + EPB; if (lim > N_EDGES) lim = N_EDGES;
    const long long* e64 = (const long long*)e32;
    for (int i = base + t; i < lim; i += 256) {
        int d = isI64 ? (int)e64[N_EDGES + i] : e32[N_EDGES + i];
        atomicAdd(&lc[d >> 8], 1);
    }
    __syncthreads();
    for (int b = t; b < NBUCK; b += 256)
        blockBase[blockIdx.x * NBUCK + b] = atomicAdd(&gcount[b], lc[b]);
}

// ---------- scan 391 bucket counts -> bucketStart; also row_ptr[N] ----------
__global__ void k_scanb(const int* __restrict__ gcount, int* __restrict__ bucketStart,
                        int* __restrict__ row_ptr) {
    __shared__ int s[512];
    int t = threadIdx.x;
    s[t] = (t < NBUCK) ? gcount[t] : 0;
    __syncthreads();
    for (int o = 1; o < 512; o <<= 1) {
        int v = s[t]; int a = (t >= o) ? s[t - o] : 0;
        __syncthreads(); s[t] = v + a; __syncthreads();
    }
    if (t < NBUCK) bucketStart[t + 1] = s[t];
    if (t == 0) { bucketStart[0] = 0; row_ptr[N_NODES] = N_EDGES; }
}

// ---------- phase B: scatter (src,dst) pairs into bucket-major order ----------
__global__ void k_scatterB(const int* __restrict__ e32, const int* __restrict__ flag,
                           const int* __restrict__ bucketStart, const int* __restrict__ blockBase,
                           int2* __restrict__ pairs) {
    __shared__ int lcur[NBUCK];
    int t = threadIdx.x;
    for (int b = t; b < NBUCK; b += 256)
        lcur[b] = bucketStart[b] + blockBase[blockIdx.x * NBUCK + b];
    __syncthreads();
    int isI64 = flag[0];
    int base = blockIdx.x * EPB;
    int lim = base + EPB; if (lim > N_EDGES) lim = N_EDGES;
    const long long* e64 = (const long long*)e32;
    for (int i = base + t; i < lim; i += 256) {
        int s, d;
        if (isI64) { s = (int)e64[i]; d = (int)e64[N_EDGES + i]; }
        else       { s = e32[i];      d = e32[N_EDGES + i]; }
        int pos = atomicAdd(&lcur[d >> 8], 1);
        pairs[pos] = make_int2(s, d);     // ~42-edge contiguous runs per (block,bucket)
    }
}

// ---------- phase C: per-bucket counting sort in LDS -> esrc + row_ptr ----------
__global__ void k_sortB(const int2* __restrict__ pairs, const int* __restrict__ bucketStart,
                        int* __restrict__ row_ptr, int* __restrict__ esrc) {
    __shared__ int srcb[CAP];       // packed: src | (local_dst<<20)
    __shared__ int cnt[256];
    __shared__ int scn[256];
    int t = threadIdx.x;
    int b = blockIdx.x;
    int s0 = bucketStart[b], s1 = bucketStart[b + 1];
    int n = s1 - s0; if (n > CAP) n = CAP;   // never triggers (32-sigma margin)
    cnt[t] = 0;
    __syncthreads();
    for (int i = t; i < n; i += 256) {
        int2 p = pairs[s0 + i];
        int ld = p.y & 255;
        srcb[i] = p.x | (ld << 20);
        atomicAdd(&cnt[ld], 1);
    }
    __syncthreads();
    // exclusive scan of cnt
    scn[t] = cnt[t];
    __syncthreads();
    for (int o = 1; o < 256; o <<= 1) {
        int v = scn[t]; int a = (t >= o) ? scn[t - o] : 0;
        __syncthreads(); scn[t] = v + a; __syncthreads();
    }
    int excl = scn[t] - cnt[t];
    int node = b * 256 + t;
    if (node < N_NODES) row_ptr[node] = s0 + excl;
    __syncthreads();
    cnt[t] = excl;                  // reuse as cursor
    __syncthreads();
    for (int i = t; i < n; i += 256) {
        int v = srcb[i];
        int ld = v >> 20;
        int r = atomicAdd(&cnt[ld], 1);
        esrc[s0 + r] = v & 0xFFFFF; // 16KB window, single block/XCD -> L2 absorbs
    }
}

// ---------- W prep: pack [Wrel1 ; Wroot1] as bf16 frag-layout Wpk[k>>3][n][k&7] ----------
__global__ void k_prepw(const float* __restrict__ Wrel1, const float* __restrict__ Wroot1,
                        unsigned short* __restrict__ Wpk) {
    int idx = blockIdx.x * 256 + threadIdx.x;
    if (idx < (K_PAD / 8) * 256 * 8) {
        int j = idx & 7;
        int n = (idx >> 3) & 255;
        int p = idx >> 11;
        int k = p * 8 + j;
        float v = 0.f;
        if (k < DIM_IN) v = (n < 128) ? Wrel1[n * DIM_IN + k] : Wroot1[(n - 128) * DIM_IN + k];
        unsigned u = __float_as_uint(v);
        u += 0x7FFFu + ((u >> 16) & 1u);     // RNE to bf16
        Wpk[idx] = (unsigned short)(u >> 16);
    }
}

// ---------- layer-1 via MFMA: [y_rel | y_root] = x @ [Wrel1;Wroot1]^T ----------
// x split hi+lo bf16 (2 MFMA passes, same acc). y_rel bf16, y_root fp32.
__launch_bounds__(256, 4)
__global__ void k_gemm_mfma(const float* __restrict__ x, const unsigned short* __restrict__ Wpk,
                            unsigned short* __restrict__ y_rel, float* __restrict__ y_root) {
    __shared__ unsigned short lh[32][232];
    __shared__ unsigned short ll[32][232];
    int tid = threadIdx.x;
    int base = blockIdx.x * 32;

    const float4* xg = (const float4*)(x + (size_t)base * DIM_IN);
    for (int i = tid; i < 1320; i += 256) {
        float4 v = xg[i];
        int fi = i * 4;
        #pragma unroll
        for (int e = 0; e < 4; ++e) {
            int idx = fi + e;
            int r = idx / DIM_IN;
            int k = idx - r * DIM_IN;
            float f = (e == 0) ? v.x : (e == 1) ? v.y : (e == 2) ? v.z : v.w;
            unsigned u = __float_as_uint(f);
            unsigned short hi = (unsigned short)(u >> 16);
            float fhi = __uint_as_float(u & 0xFFFF0000u);
            float lo = f - fhi;
            unsigned short lob = (unsigned short)(__float_as_uint(lo) >> 16);
            lh[r][k] = hi;
            ll[r][k] = lob;
        }
    }
    for (int i = tid; i < 32 * (K_PAD - DIM_IN); i += 256) {
        int r = i / (K_PAD - DIM_IN);
        int k = DIM_IN + (i - r * (K_PAD - DIM_IN));
        lh[r][k] = 0; ll[r][k] = 0;
    }
    __syncthreads();

    int w = tid >> 6, l = tid & 63;
    int rowg = w & 1;
    int colh = w >> 1;
    int m = l & 15, kg = l >> 4;
    int arow = rowg * 16 + m;

    f32x4 acc[8];
    #pragma unroll
    for (int t = 0; t < 8; ++t) acc[t] = (f32x4){0.f, 0.f, 0.f, 0.f};

    const short8v* ap_h = (const short8v*)(&lh[arow][0]);
    const short8v* ap_l = (const short8v*)(&ll[arow][0]);
    const short8v* bp   = (const short8v*)Wpk;
    int bidx = kg * 256 + colh * 128 + m;

    #pragma unroll
    for (int kc = 0; kc < 6; ++kc) {
        short8v ah = ap_h[kc * 4 + kg];
        short8v al = ap_l[kc * 4 + kg];
        short8v bfrag[8];
        #pragma unroll
        for (int t = 0; t < 8; ++t) bfrag[t] = bp[bidx + kc * 1024 + t * 16];
        #pragma unroll
        for (int t = 0; t < 8; ++t)
            acc[t] = __builtin_amdgcn_mfma_f32_16x16x32_bf16(ah, bfrag[t], acc[t], 0, 0, 0);
        #pragma unroll
        for (int t = 0; t < 8; ++t)
            acc[t] = __builtin_amdgcn_mfma_f32_16x16x32_bf16(al, bfrag[t], acc[t], 0, 0, 0);
    }

    int orow = base + rowg * 16 + kg * 4;
    if (colh == 0) {
        #pragma unroll
        for (int t = 0; t < 8; ++t) {
            #pragma unroll
            for (int q = 0; q < 4; ++q) {
                unsigned u = __float_as_uint(acc[t][q]);
                u += 0x7FFFu + ((u >> 16) & 1u);
                y_rel[(size_t)(orow + q) * 128 + t * 16 + m] = (unsigned short)(u >> 16);
            }
        }
    } else {
        #pragma unroll
        for (int t = 0; t < 8; ++t) {
            #pragma unroll
            for (int q = 0; q < 4; ++q)
                y_root[(size_t)(orow + q) * 128 + t * 16 + m] = acc[t][q];
        }
    }
}

// ---------- fused: agg = sum y_rel[j] (bf16 gather, fp32 accum); h = relu(agg+b+y_root);
//            s = h.W_rel2; r = h.W_root2 (one wave per node) ----------
__launch_bounds__(256, 2)
__global__ void k_agg(const unsigned short* __restrict__ y_rel, const float* __restrict__ y_root,
                      const int* __restrict__ row_ptr, const int* __restrict__ esrc,
                      const float* __restrict__ b_rel1, const float* __restrict__ W_rel2,
                      const float* __restrict__ W_root2,
                      float* __restrict__ s_out, float* __restrict__ r_out) {
    int node = blockIdx.x * 4 + (threadIdx.x >> 6);
    int lane = threadIdx.x & 63;
    const unsigned* yr = (const unsigned*)y_rel;
    int e0 = row_ptr[node], e1 = row_ptr[node + 1];
    float ax0 = 0.f, ay0 = 0.f, ax1 = 0.f, ay1 = 0.f;
    float ax2 = 0.f, ay2 = 0.f, ax3 = 0.f, ay3 = 0.f;
    int e = e0;
    for (; e + 3 < e1; e += 4) {
        int s0 = esrc[e], s1 = esrc[e + 1], s2 = esrc[e + 2], s3 = esrc[e + 3];
        unsigned v0 = yr[(size_t)s0 * 64 + lane];
        unsigned v1 = yr[(size_t)s1 * 64 + lane];
        unsigned v2 = yr[(size_t)s2 * 64 + lane];
        unsigned v3 = yr[(size_t)s3 * 64 + lane];
        ax0 += __uint_as_float(v0 << 16); ay0 += __uint_as_float(v0 & 0xFFFF0000u);
        ax1 += __uint_as_float(v1 << 16); ay1 += __uint_as_float(v1 & 0xFFFF0000u);
        ax2 += __uint_as_float(v2 << 16); ay2 += __uint_as_float(v2 & 0xFFFF0000u);
        ax3 += __uint_as_float(v3 << 16); ay3 += __uint_as_float(v3 & 0xFFFF0000u);
    }
    for (; e < e1; ++e) {
        unsigned v0 = yr[(size_t)esrc[e] * 64 + lane];
        ax0 += __uint_as_float(v0 << 16); ay0 += __uint_as_float(v0 & 0xFFFF0000u);
    }
    float ax = (ax0 + ax1) + (ax2 + ax3);
    float ay = (ay0 + ay1) + (ay2 + ay3);

    float2 b2 = ((const float2*)b_rel1)[lane];
    float2 rt = ((const float2*)y_root)[(size_t)node * 64 + lane];
    float hx = ax + b2.x + rt.x; hx = hx > 0.f ? hx : 0.f;
    float hy = ay + b2.y + rt.y; hy = hy > 0.f ? hy : 0.f;
    float2 wr2 = ((const float2*)W_rel2)[lane];
    float2 wo2 = ((const float2*)W_root2)[lane];
    float sd = fmaf(hx, wr2.x, hy * wr2.y);
    float rd = fmaf(hx, wo2.x, hy * wo2.y);
    #pragma unroll
    for (int o = 32; o > 0; o >>= 1) {
        sd += __shfl_down(sd, o);
        rd += __shfl_down(rd, o);
    }
    if (lane == 0) { s_out[node] = sd; r_out[node] = rd; }
}

// ---------- final: out[i] = sigmoid(sum_{j->i} s[j] + b2 + r[i]) ----------
__global__ void k_final(const float* __restrict__ s_in, const float* __restrict__ r_in,
                        const int* __restrict__ row_ptr, const int* __restrict__ esrc,
                        const float* __restrict__ b_rel2, float* __restrict__ out) {
    int i = blockIdx.x * blockDim.x + threadIdx.x;
    if (i < N_NODES) {
        int e0 = row_ptr[i], e1 = row_ptr[i + 1];
        float sum = 0.f;
        for (int e = e0; e < e1; ++e) sum += s_in[esrc[e]];
        float z = sum + b_rel2[0] + r_in[i];
        out[i] = 1.f / (1.f + expf(-z));
    }
}

extern "C" void kernel_launch(void* const* d_in, const int* in_sizes, int n_in,
                              void* d_out, int out_size, void* d_ws, size_t ws_size,
                              hipStream_t stream) {
    const float* x      = (const float*)d_in[0];
    const int*   eidx   = (const int*)d_in[1];
    const float* Wrel1  = (const float*)d_in[2];
    const float* brel1  = (const float*)d_in[3];
    const float* Wroot1 = (const float*)d_in[4];
    const float* Wrel2  = (const float*)d_in[5];
    const float* brel2  = (const float*)d_in[6];
    const float* Wroot2 = (const float*)d_in[7];
    float* out = (float*)d_out;

    char* basep = (char*)d_ws;
    size_t off = 0;
    auto alloc = [&](size_t bytes) -> void* {
        off = (off + 511) & ~(size_t)511;
        void* r = basep + off;
        off += bytes;
        return r;
    };
    // --- persistent ---
    int*   flag        = (int*)alloc(4);
    unsigned short* Wpk = (unsigned short*)alloc((size_t)(K_PAD / 8) * 256 * 8 * 2);
    int*   row_ptr     = (int*)alloc((size_t)(N_NODES + 1) * 4);
    int*   esrc        = (int*)alloc((size_t)N_EDGES * 4);
    float* s_buf       = (float*)alloc((size_t)N_NODES * 4);
    float* r_buf       = (float*)alloc((size_t)N_NODES * 4);
    int*   bucketStart = (int*)alloc((size_t)(NBUCK + 1) * 4);
    int*   gcount      = (int*)alloc((size_t)NBUCK * 4);
    // --- union region: sort scratch (dead after k_sortB) vs GEMM outputs ---
    size_t union_base = (off + 511) & ~(size_t)511;
    off = union_base;
    int2*  pairs     = (int2*)alloc((size_t)N_EDGES * 8);
    int*   blockBase = (int*)alloc((size_t)NHB * NBUCK * 4);
    off = union_base;
    unsigned short* y_rel  = (unsigned short*)alloc((size_t)N_NODES * DIM_HID * 2);
    float*          y_root = (float*)alloc((size_t)N_NODES * DIM_HID * 4);

    hipLaunchKernelGGL(k_detect,   dim3(1),     dim3(512), 0, stream, eidx, flag, gcount);
    hipLaunchKernelGGL(k_histB,    dim3(NHB),   dim3(256), 0, stream, eidx, flag, gcount, blockBase);
    hipLaunchKernelGGL(k_scanb,    dim3(1),     dim3(512), 0, stream, gcount, bucketStart, row_ptr);
    hipLaunchKernelGGL(k_scatterB, dim3(NHB),   dim3(256), 0, stream, eidx, flag, bucketStart, blockBase, pairs);
    hipLaunchKernelGGL(k_sortB,    dim3(NBUCK), dim3(256), 0, stream, pairs, bucketStart, row_ptr, esrc);
    hipLaunchKernelGGL(k_prepw,    dim3(192),   dim3(256), 0, stream, Wrel1, Wroot1, Wpk);
    hipLaunchKernelGGL(k_gemm_mfma,dim3(3125),  dim3(256), 0, stream, x, Wpk, y_rel, y_root);
    hipLaunchKernelGGL(k_agg,      dim3(25000), dim3(256), 0, stream, y_rel, y_root, row_ptr, esrc,
                       brel1, Wrel2, Wroot2, s_buf, r_buf);
    hipLaunchKernelGGL(k_final,    dim3(391),   dim3(256), 0, stream, s_buf, r_buf, row_ptr, esrc,
                       brel2, out);
}